// Round 5
// baseline (335.777 us; speedup 1.0000x reference)
//
#include <hip/hip_runtime.h>

typedef _Float16 half8 __attribute__((ext_vector_type(8)));
typedef _Float16 half4v __attribute__((ext_vector_type(4)));
typedef float f32x4 __attribute__((ext_vector_type(4)));

#define ZQ_ELEMS 8388608   // 32*256*32*32
#define N_TOK    32768
#define D_DIM    256
#define K_CB     1024

#define FLAG_CAP 8192      // observed cnt ~730 (deterministic input); 11x margin
#define ESCALE   1024.0f
#define TAU      0.15f     // flag margin (scaled units)
#define FIX_GRID 1536

__device__ __align__(16) _Float16 g_eh[K_CB * D_DIM];  // fp16(1024*e)
__device__ __align__(16) float g_ebT[D_DIM * K_CB];    // emb transposed [d][k], 1 MB
__device__ float g_ck[K_CB];                            // 512*||e_k||^2 (prefilter)
__device__ float g_bk[K_CB];                            // f32(sum e^2), np-style B_k
__device__ float g_loss;
__device__ int   g_cnt;
__device__ int   g_fixdone;
__device__ int   g_flags[FLAG_CAP];
__device__ float g_zst[FLAG_CAP * 256];                 // staged z rows (coalesced)
__device__ float g_aA[FLAG_CAP];                        // A_n per flagged token
__device__ unsigned long long g_best[FLAG_CAP];         // (orderedD<<32)|k, atomicMin

__device__ __forceinline__ unsigned long long enc_dk(float D, int k) {
  unsigned int b = __float_as_uint(D);
  unsigned int u = (b & 0x80000000u) ? ~b : (b | 0x80000000u);  // order-preserving
  return (((unsigned long long)u) << 32) | (unsigned int)k;
}

// prep: tables + zero accumulators + reset g_best + emb transpose
__global__ __launch_bounds__(256) void vq_prep(const float* __restrict__ emb) {
  __shared__ float tl[64][65];
  const int tid = threadIdx.x;
  const int w   = tid >> 6;
  const int l   = tid & 63;
  const int k   = (blockIdx.x << 2) + w;          // 256 blocks * 4 waves
  f32x4 v = *(const f32x4*)(emb + (k << 8) + (l << 2));
  double sd = (double)v[0]*v[0] + (double)v[1]*v[1] + (double)v[2]*v[2] + (double)v[3]*v[3];
  #pragma unroll
  for (int m = 1; m < 64; m <<= 1) sd += __shfl_xor(sd, m);
  if (l == 0) { g_bk[k] = (float)sd; g_ck[k] = 512.0f * (float)sd; }
  half4v h;
  h[0] = (_Float16)(v[0] * ESCALE); h[1] = (_Float16)(v[1] * ESCALE);
  h[2] = (_Float16)(v[2] * ESCALE); h[3] = (_Float16)(v[3] * ESCALE);
  *(half4v*)(g_eh + (k << 8) + (l << 2)) = h;
  const int gi = blockIdx.x * 256 + tid;
  if (gi < FLAG_CAP) g_best[gi] = ~0ULL;
  if (blockIdx.x == 0 && tid == 0) { g_loss = 0.0f; g_cnt = 0; g_fixdone = 0; }
  // transpose tile (blocks 0..63): emb [k][d] -> g_ebT [d][k]
  if (blockIdx.x < 64) {
    const int tx = tid & 63, ty = tid >> 6;
    const int k0 = (blockIdx.x & 15) << 6;
    const int d0 = (blockIdx.x >> 4) << 6;
    #pragma unroll
    for (int j = 0; j < 16; j++) {
      const int kk = (ty << 4) + j;
      tl[kk][tx] = emb[((k0 + kk) << 8) + d0 + tx];
    }
    __syncthreads();
    #pragma unroll
    for (int j = 0; j < 16; j++) {
      const int dd = (ty << 4) + j;
      g_ebT[((d0 + dd) << 10) + k0 + tx] = tl[tx][dd];
    }
  }
}

// main: 64 tokens/block, 8 waves, each owning 1/8 of K with the r0-proven
// single-k-tile inner body (acc[4] live only, ~108 VGPR measured).
// __launch_bounds__(512,2): hipcc arg2 = min BLOCKS/CU -> VGPR cap 128,
// 2 blocks/CU = 16 waves/CU (2x r0's concurrency at r0's per-block traffic).
__global__ __launch_bounds__(512, 2) void vq_main(const float* __restrict__ x,
                                                  const float* __restrict__ emb,
                                                  float* __restrict__ out) {
  __shared__ __align__(16) _Float16 zt[64 * 256];   // 32 KB, XOR-swizzled
  __shared__ float ckl[K_CB];                        // 4 KB; reused as zl in staging
  __shared__ float wv1[8][64], wv2[8][64];
  __shared__ int   wi1[8][64];
  __shared__ int   fidx[64];
  __shared__ float lred[8];
  __shared__ int   fcnt;
  __shared__ int   fslot[64], ftok[64];

  const int tid = threadIdx.x;
  const int n0  = blockIdx.x << 6;
  const int b   = blockIdx.x >> 4;
  const int hw0 = (blockIdx.x & 15) << 6;

  if (tid == 0) fcnt = 0;
  ckl[tid] = g_ck[tid];
  ckl[tid + 512] = g_ck[tid + 512];

  // stage x tile -> fp16; (n,d) lives at n*256 + (((d>>3)^(n&7)^(n>>3))<<3) + (d&7)
  {
    const int hw8 = (tid & 7) << 3;
    const int dl  = tid >> 3;               // 0..63
    #pragma unroll
    for (int it = 0; it < 4; it++) {
      const int d = (it << 6) + dl;
      const float* src = x + (((b << 8) + d) << 10) + hw0 + hw8;
      f32x4 a0 = *(const f32x4*)src;
      f32x4 a1 = *(const f32x4*)(src + 4);
      _Float16 cv[8];
      cv[0]=(_Float16)a0[0]; cv[1]=(_Float16)a0[1]; cv[2]=(_Float16)a0[2]; cv[3]=(_Float16)a0[3];
      cv[4]=(_Float16)a1[0]; cv[5]=(_Float16)a1[1]; cv[6]=(_Float16)a1[2]; cv[7]=(_Float16)a1[3];
      const int blkx = d >> 3;
      #pragma unroll
      for (int i = 0; i < 8; i++) {
        const int n   = hw8 + i;                    // n&7 = i, n>>3 = tid&7
        const int blk = blkx ^ i ^ (tid & 7);
        zt[(n << 8) + (blk << 3) + (d & 7)] = cv[i];
      }
    }
  }
  __syncthreads();

  const int w = tid >> 6;                   // 0..7
  const int l = tid & 63;
  const int c = l & 15;
  const int q = l >> 4;

  float v1[4][4], v2[4][4]; int i1[4][4];
  #pragma unroll
  for (int t = 0; t < 4; t++)
    #pragma unroll
    for (int r = 0; r < 4; r++) { v1[t][r] = -3e38f; v2[t][r] = -3e38f; i1[t][r] = 0; }

  // K loop: wave w owns k = w*16 + jj*128 + c  (8 jj, single k-tile per pass)
  for (int jj = 0; jj < 8; jj++) {
    const int k0 = (w << 4) + (jj << 7);
    const int kk = k0 + c;
    const float ckv = ckl[kk];
    f32x4 acc[4];
    #pragma unroll
    for (int t = 0; t < 4; t++) acc[t] = f32x4{-ckv, -ckv, -ckv, -ckv};
    #pragma unroll
    for (int s = 0; s < 8; s++) {
      const half8 bf = *(const half8*)(g_eh + (kk << 8) + (s << 5) + (q << 3));
      #pragma unroll
      for (int t = 0; t < 4; t++) {
        const int n  = (t << 4) + c;
        const int sw = (n & 7) ^ (n >> 3);
        const half8 a = *(const half8*)(zt + (n << 8) + ((((s << 2) + q) ^ sw) << 3));
        acc[t] = __builtin_amdgcn_mfma_f32_16x16x32_f16(a, bf, acc[t], 0, 0, 0);
      }
    }
    #pragma unroll
    for (int t = 0; t < 4; t++)
      #pragma unroll
      for (int r = 0; r < 4; r++) {
        const float sv = acc[t][r];
        if (sv > v1[t][r]) { v2[t][r] = v1[t][r]; v1[t][r] = sv; i1[t][r] = kk; }
        else if (sv > v2[t][r]) v2[t][r] = sv;
      }
  }

  // top-2 merge across the 16 column lanes, then across 8 waves
  #pragma unroll
  for (int t = 0; t < 4; t++)
    #pragma unroll
    for (int r = 0; r < 4; r++) {
      float a1v = v1[t][r], a2v = v2[t][r]; int ai = i1[t][r];
      #pragma unroll
      for (int m = 8; m >= 1; m >>= 1) {
        const float o1 = __shfl_xor(a1v, m);
        const int   oi = __shfl_xor(ai, m);
        const float o2 = __shfl_xor(a2v, m);
        if (o1 > a1v || (o1 == a1v && oi < ai)) { a2v = fmaxf(a1v, o2); a1v = o1; ai = oi; }
        else a2v = fmaxf(a2v, o1);
      }
      if (c == 0) {
        const int nl = (t << 4) + (q << 2) + r;
        wv1[w][nl] = a1v; wv2[w][nl] = a2v; wi1[w][nl] = ai;
      }
    }
  __syncthreads();

  if (tid < 64) {
    float a1v = wv1[0][tid], a2v = wv2[0][tid]; int ai = wi1[0][tid];
    #pragma unroll
    for (int ww = 1; ww < 8; ww++) {
      const float o1 = wv1[ww][tid]; const int oi = wi1[ww][tid]; const float o2 = wv2[ww][tid];
      if (o1 > a1v || (o1 == a1v && oi < ai)) { a2v = fmaxf(a1v, o2); a1v = o1; ai = oi; }
      else a2v = fmaxf(a2v, o1);
    }
    fidx[tid] = ai;
    out[ZQ_ELEMS + n0 + tid] = (float)ai;        // idx as f32
    if (a1v - a2v < TAU) {                       // ambiguous -> np-replicated pass 2
      int p = atomicAdd(&g_cnt, 1);
      if (p < FLAG_CAP) {
        g_flags[p] = n0 + tid;
        int lp = atomicAdd(&fcnt, 1);
        fslot[lp] = p; ftok[lp] = n0 + tid;
      }
    }
  }
  __syncthreads();

  // gather e[idx] (f32), write z_quant f32 (coalesced over hw), accumulate loss
  float lacc = 0.0f;
  {
    const int hw = tid & 63;
    const int g  = tid >> 6;                     // 0..7; groups own disjoint dblk
    const int sw = (hw & 7) ^ (hw >> 3);
    const float* erow = emb + (fidx[hw] << 8);
    #pragma unroll
    for (int it = 0; it < 4; it++) {
      const int dblk = (it << 3) + g;            // 0..31
      half8 zv = *(const half8*)(zt + (hw << 8) + ((dblk ^ sw) << 3));
      f32x4 e0 = *(const f32x4*)(erow + (dblk << 3));
      f32x4 e1 = *(const f32x4*)(erow + (dblk << 3) + 4);
      #pragma unroll
      for (int j = 0; j < 8; j++) {
        const int d = (dblk << 3) + j;
        const float ef = (j < 4) ? e0[j] : e1[j - 4];
        const float df = ef - (float)zv[j];
        lacc += df * df;
        out[(((b << 8) + d) << 10) + hw0 + hw] = ef;
      }
    }
  }
  #pragma unroll
  for (int m = 1; m < 64; m <<= 1) lacc += __shfl_xor(lacc, m);
  if (l == 0) lred[w] = lacc;
  __syncthreads();
  if (tid == 0) {
    float ls = 0.0f;
    #pragma unroll
    for (int i = 0; i < 8; i++) ls += lred[i];
    atomicAdd(&g_loss, ls);
  }

  // inline staging of this block's flagged tokens: exact f32 x re-read ->
  // coalesced g_zst row; A_n with the SAME f64 op order as pass 2.
  const int nf = fcnt;
  for (int f = 0; f < nf; f++) {
    const int s = fslot[f];
    const int n = ftok[f];
    const int bb = n >> 10, hw = n & 1023;
    if (tid < 256) {
      const float zv = x[(((bb << 8) + tid) << 10) + hw];
      g_zst[(s << 8) + tid] = zv;
      ckl[tid] = zv;                             // ckl reused as zl
    }
    __syncthreads();
    if (tid < 32) {
      double sa = 0.0;
      #pragma unroll
      for (int j = 0; j < 8; j++) { const double z = (double)ckl[(tid << 3) + j]; sa += z * z; }
      #pragma unroll
      for (int m = 1; m < 32; m <<= 1) sa += __shfl_xor(sa, m);
      if (tid == 0) g_aA[s] = (float)sa;
    }
    __syncthreads();
  }
}

// pass 2: job = (token-PAIR, r-quarter) -> njob = ceil(cnt/2)*4 ~ 1464 over
// 1536 blocks = 6 blocks/CU (vs r4's 3): latency of the serial f64 chains is
// hidden by occupancy. Lane owns k = r*256+tid; d-ascending f64 fma chain
// (bit-identical D). Barrier-free wave shfl min-reduce + 4-way cross-wave
// merge (same (v,k) tie-break as the old tree). Last block finalizes.
__global__ __launch_bounds__(256) void vq_fix(const float* __restrict__ emb,
                                              float* __restrict__ out) {
  __shared__ float z0l[256], z1l[256];
  __shared__ float rv[2][4];
  __shared__ int   rk[2][4];
  __shared__ unsigned int chmask[FLAG_CAP / 32];   // 1 KB changed-token bitmap
  __shared__ int   lastflag;
  const int tid = threadIdx.x;
  int cnt = g_cnt; if (cnt > FLAG_CAP) cnt = FLAG_CAP;
  const int njob = ((cnt + 1) >> 1) << 2;
  for (int j = blockIdx.x; j < njob; j += gridDim.x) {
    const int pr = j >> 2, r = j & 3;
    const int s0 = pr << 1;
    const int s1 = (s0 + 1 < cnt) ? s0 + 1 : cnt - 1;
    z0l[tid] = g_zst[(s0 << 8) + tid];
    z1l[tid] = g_zst[(s1 << 8) + tid];
    __syncthreads();
    double c0 = 0.0, c1 = 0.0;
    const float* colbase = g_ebT + (r << 8) + tid;
    #pragma unroll 8
    for (int d = 0; d < 256; d++) {
      const double e = (double)colbase[d << 10];    // coalesced over tid
      c0 = fma(e, (double)z0l[d], c0);
      c1 = fma(e, (double)z1l[d], c1);
    }
    const int k = (r << 8) + tid;
    const float bkv = g_bk[k];
    float b0 = (g_aA[s0] + bkv) - 2.0f * (float)c0;
    float b1 = (g_aA[s1] + bkv) - 2.0f * (float)c1;
    int k0i = k, k1i = k;
    #pragma unroll
    for (int m = 1; m < 64; m <<= 1) {
      const float o0 = __shfl_xor(b0, m); const int ok0 = __shfl_xor(k0i, m);
      const float o1 = __shfl_xor(b1, m); const int ok1 = __shfl_xor(k1i, m);
      if (o0 < b0 || (o0 == b0 && ok0 < k0i)) { b0 = o0; k0i = ok0; }
      if (o1 < b1 || (o1 == b1 && ok1 < k1i)) { b1 = o1; k1i = ok1; }
    }
    const int wv = tid >> 6;
    if ((tid & 63) == 0) { rv[0][wv] = b0; rk[0][wv] = k0i; rv[1][wv] = b1; rk[1][wv] = k1i; }
    __syncthreads();
    if (tid == 0) {
      float fb0 = rv[0][0]; int fk0 = rk[0][0];
      float fb1 = rv[1][0]; int fk1 = rk[1][0];
      #pragma unroll
      for (int ww = 1; ww < 4; ww++) {
        if (rv[0][ww] < fb0 || (rv[0][ww] == fb0 && rk[0][ww] < fk0)) { fb0 = rv[0][ww]; fk0 = rk[0][ww]; }
        if (rv[1][ww] < fb1 || (rv[1][ww] == fb1 && rk[1][ww] < fk1)) { fb1 = rv[1][ww]; fk1 = rk[1][ww]; }
      }
      atomicMin(&g_best[s0], enc_dk(fb0, fk0));
      atomicMin(&g_best[s1], enc_dk(fb1, fk1));
    }
    __syncthreads();
  }

  // last-block finalize (device-scope atomics; g_best re-read atomically)
  __threadfence();
  if (tid == 0) lastflag = (atomicAdd(&g_fixdone, 1) == (int)gridDim.x - 1);
  __syncthreads();
  if (!lastflag) return;
  if (tid == 0) out[ZQ_ELEMS + N_TOK] = g_loss * (1.25f / 8388608.0f);
  for (int i = tid; i < FLAG_CAP / 32; i += 256) chmask[i] = 0u;
  __syncthreads();
  for (int s = tid; s < cnt; s += 256) {
    const int n = g_flags[s];
    const unsigned long long bv = atomicMin(&g_best[s], ~0ULL);  // coherent read
    const int kw = (int)(unsigned int)(bv & 0xFFFFFFFFu);
    const int kold = (int)out[ZQ_ELEMS + n];
    out[ZQ_ELEMS + n] = (float)kw;
    if (kw != kold) {
      g_flags[s] = (int)(((unsigned)n) | ((unsigned)kw << 15) | 0x80000000u);
      atomicOr(&chmask[s >> 5], 1u << (s & 31));
    }
  }
  __syncthreads();
  const int nw = (cnt + 31) >> 5;
  for (int wd = 0; wd < nw; wd++) {
    unsigned int m = chmask[wd];
    while (m) {
      const int bpos = __ffs(m) - 1;
      m &= m - 1;
      const int s = (wd << 5) + bpos;
      const unsigned pv = (unsigned)g_flags[s];    // written by this block, post-barrier
      const int n  = (int)(pv & 0x7FFFu);
      const int kw = (int)((pv >> 15) & 0x3FFu);
      const int bb = n >> 10, hw = n & 1023;
      out[(((bb << 8) + tid) << 10) + hw] = emb[(kw << 8) + tid];
    }
  }
}

extern "C" void kernel_launch(void* const* d_in, const int* in_sizes, int n_in,
                              void* d_out, int out_size, void* d_ws, size_t ws_size,
                              hipStream_t stream) {
  const float* x   = (const float*)d_in[0];
  const float* emb = (const float*)d_in[1];
  float* out = (float*)d_out;
  vq_prep<<<256, 256, 0, stream>>>(emb);
  vq_main<<<512, 512, 0, stream>>>(x, emb, out);
  vq_fix<<<FIX_GRID, 256, 0, stream>>>(emb, out);
}

// Round 6
// 260.838 us; speedup vs baseline: 1.2873x; 1.2873x over previous
//
#include <hip/hip_runtime.h>

typedef _Float16 half8 __attribute__((ext_vector_type(8)));
typedef _Float16 half4v __attribute__((ext_vector_type(4)));
typedef float f32x4 __attribute__((ext_vector_type(4)));

#define ZQ_ELEMS 8388608   // 32*256*32*32
#define N_TOK    32768
#define D_DIM    256
#define K_CB     1024

#define FLAG_CAP 8192      // observed cnt ~730 (deterministic input); 11x margin
#define ESCALE   1024.0f
#define TAU      0.15f     // flag margin (scaled units)
#define FIX_GRID 768

__device__ __align__(16) _Float16 g_eh[K_CB * D_DIM];  // fp16(1024*e)
__device__ __align__(16) float g_ebT[D_DIM * K_CB];    // emb transposed [d][k], 1 MB
__device__ float g_ck[K_CB];                            // 512*||e_k||^2 (prefilter)
__device__ float g_bk[K_CB];                            // f32(sum e^2), np-style B_k
__device__ float g_loss;
__device__ int   g_cnt;
__device__ int   g_fixdone;
__device__ int   g_flags[FLAG_CAP];
__device__ float g_zst[FLAG_CAP * 256];                 // staged z rows (coalesced)
__device__ float g_aA[FLAG_CAP];                        // A_n per flagged token
__device__ unsigned long long g_best[FLAG_CAP];         // (orderedD<<32)|k, atomicMin

__device__ __forceinline__ unsigned long long enc_dk(float D, int k) {
  unsigned int b = __float_as_uint(D);
  unsigned int u = (b & 0x80000000u) ? ~b : (b | 0x80000000u);  // order-preserving
  return (((unsigned long long)u) << 32) | (unsigned int)k;
}

// prep: tables + zero accumulators + reset g_best + emb transpose
__global__ __launch_bounds__(256) void vq_prep(const float* __restrict__ emb) {
  __shared__ float tl[64][65];
  const int tid = threadIdx.x;
  const int w   = tid >> 6;
  const int l   = tid & 63;
  const int k   = (blockIdx.x << 2) + w;          // 256 blocks * 4 waves
  f32x4 v = *(const f32x4*)(emb + (k << 8) + (l << 2));
  double sd = (double)v[0]*v[0] + (double)v[1]*v[1] + (double)v[2]*v[2] + (double)v[3]*v[3];
  #pragma unroll
  for (int m = 1; m < 64; m <<= 1) sd += __shfl_xor(sd, m);
  if (l == 0) { g_bk[k] = (float)sd; g_ck[k] = 512.0f * (float)sd; }
  half4v h;
  h[0] = (_Float16)(v[0] * ESCALE); h[1] = (_Float16)(v[1] * ESCALE);
  h[2] = (_Float16)(v[2] * ESCALE); h[3] = (_Float16)(v[3] * ESCALE);
  *(half4v*)(g_eh + (k << 8) + (l << 2)) = h;
  const int gi = blockIdx.x * 256 + tid;
  if (gi < FLAG_CAP) g_best[gi] = ~0ULL;
  if (blockIdx.x == 0 && tid == 0) { g_loss = 0.0f; g_cnt = 0; g_fixdone = 0; }
  // transpose tile (blocks 0..63): emb [k][d] -> g_ebT [d][k]
  if (blockIdx.x < 64) {
    const int tx = tid & 63, ty = tid >> 6;
    const int k0 = (blockIdx.x & 15) << 6;
    const int d0 = (blockIdx.x >> 4) << 6;
    #pragma unroll
    for (int j = 0; j < 16; j++) {
      const int kk = (ty << 4) + j;
      tl[kk][tx] = emb[((k0 + kk) << 8) + d0 + tx];
    }
    __syncthreads();
    #pragma unroll
    for (int j = 0; j < 16; j++) {
      const int dd = (ty << 4) + j;
      g_ebT[((d0 + dd) << 10) + k0 + tx] = tl[tx][dd];
    }
  }
}

// main: r0-measured structure verbatim (512 blocks x 256 thr, 4 waves, 64
// tokens/block, 16 jj, VGPR 108, 63-65 us measured) + inline staging tail.
__global__ __launch_bounds__(256, 2) void vq_main(const float* __restrict__ x,
                                                  const float* __restrict__ emb,
                                                  float* __restrict__ out) {
  __shared__ __align__(16) _Float16 zt[64 * 256];   // 32 KB, XOR-swizzled
  __shared__ float ckl[K_CB];
  __shared__ float wv1[4][64], wv2[4][64];
  __shared__ int   wi1[4][64];
  __shared__ int   fidx[64];
  __shared__ float lred[4];
  __shared__ int   fcnt;
  __shared__ int   fslot[64], ftok[64];

  const int tid = threadIdx.x;
  const int n0  = blockIdx.x * 64;
  const int b   = blockIdx.x >> 4;
  const int hw0 = (blockIdx.x & 15) << 6;

  if (tid == 0) fcnt = 0;

  #pragma unroll
  for (int i = 0; i < 4; i++) ckl[tid + 256 * i] = g_ck[tid + 256 * i];

  // stage x tile -> fp16; (n,d) lives at n*256 + (((d>>3)^(n&7)^(n>>3))<<3) + (d&7)
  {
    const int hw8 = (tid & 7) << 3;
    const int dl  = tid >> 3;               // 0..31
    #pragma unroll
    for (int it = 0; it < 8; it++) {
      const int d = (it << 5) + dl;
      const float* src = x + (((b << 8) + d) << 10) + hw0 + hw8;
      f32x4 a0 = *(const f32x4*)src;
      f32x4 a1 = *(const f32x4*)(src + 4);
      _Float16 cv[8];
      cv[0]=(_Float16)a0[0]; cv[1]=(_Float16)a0[1]; cv[2]=(_Float16)a0[2]; cv[3]=(_Float16)a0[3];
      cv[4]=(_Float16)a1[0]; cv[5]=(_Float16)a1[1]; cv[6]=(_Float16)a1[2]; cv[7]=(_Float16)a1[3];
      const int blkx = d >> 3;
      #pragma unroll
      for (int i = 0; i < 8; i++) {
        const int n   = hw8 + i;
        const int blk = blkx ^ i ^ (tid & 7);
        zt[(n << 8) + (blk << 3) + (d & 7)] = cv[i];
      }
    }
  }
  __syncthreads();

  const int w = tid >> 6;
  const int l = tid & 63;
  const int c = l & 15;
  const int q = l >> 4;

  half8 af[4][8];
  #pragma unroll
  for (int t = 0; t < 4; t++) {
    const int n  = (t << 4) + c;
    const int sw = (n & 7) ^ (n >> 3);
    #pragma unroll
    for (int s = 0; s < 8; s++) {
      const int K = (s << 2) + q;
      af[t][s] = *(const half8*)(zt + (n << 8) + ((K ^ sw) << 3));
    }
  }

  float v1[4][4], v2[4][4]; int i1[4][4];
  #pragma unroll
  for (int t = 0; t < 4; t++)
    #pragma unroll
    for (int r = 0; r < 4; r++) { v1[t][r] = -3e38f; v2[t][r] = -3e38f; i1[t][r] = 0; }

  for (int jj = 0; jj < 16; jj++) {
    const int k0 = (w << 4) + (jj << 6);
    const float ckv = ckl[k0 + c];
    f32x4 acc[4];
    #pragma unroll
    for (int t = 0; t < 4; t++) acc[t] = f32x4{-ckv, -ckv, -ckv, -ckv};
    #pragma unroll
    for (int s = 0; s < 8; s++) {
      const half8 bf = *(const half8*)(g_eh + ((k0 + c) << 8) + (s << 5) + (q << 3));
      #pragma unroll
      for (int t = 0; t < 4; t++)
        acc[t] = __builtin_amdgcn_mfma_f32_16x16x32_f16(af[t][s], bf, acc[t], 0, 0, 0);
    }
    const int kk = k0 + c;
    #pragma unroll
    for (int t = 0; t < 4; t++)
      #pragma unroll
      for (int r = 0; r < 4; r++) {
        const float sv = acc[t][r];
        if (sv > v1[t][r]) { v2[t][r] = v1[t][r]; v1[t][r] = sv; i1[t][r] = kk; }
        else if (sv > v2[t][r]) v2[t][r] = sv;
      }
  }

  // top-2 merge across the 16 column lanes, then across waves
  #pragma unroll
  for (int t = 0; t < 4; t++)
    #pragma unroll
    for (int r = 0; r < 4; r++) {
      float a1v = v1[t][r], a2v = v2[t][r]; int ai = i1[t][r];
      #pragma unroll
      for (int m = 8; m >= 1; m >>= 1) {
        const float o1 = __shfl_xor(a1v, m);
        const int   oi = __shfl_xor(ai, m);
        const float o2 = __shfl_xor(a2v, m);
        if (o1 > a1v || (o1 == a1v && oi < ai)) { a2v = fmaxf(a1v, o2); a1v = o1; ai = oi; }
        else a2v = fmaxf(a2v, o1);
      }
      if (c == 0) {
        const int nl = (t << 4) + (q << 2) + r;
        wv1[w][nl] = a1v; wv2[w][nl] = a2v; wi1[w][nl] = ai;
      }
    }
  __syncthreads();

  if (tid < 64) {
    float a1v = wv1[0][tid], a2v = wv2[0][tid]; int ai = wi1[0][tid];
    #pragma unroll
    for (int ww = 1; ww < 4; ww++) {
      const float o1 = wv1[ww][tid]; const int oi = wi1[ww][tid]; const float o2 = wv2[ww][tid];
      if (o1 > a1v || (o1 == a1v && oi < ai)) { a2v = fmaxf(a1v, o2); a1v = o1; ai = oi; }
      else a2v = fmaxf(a2v, o1);
    }
    fidx[tid] = ai;
    out[ZQ_ELEMS + n0 + tid] = (float)ai;        // idx as f32
    if (a1v - a2v < TAU) {                       // ambiguous -> np-replicated pass 2
      int p = atomicAdd(&g_cnt, 1);
      if (p < FLAG_CAP) {
        g_flags[p] = n0 + tid;
        int lp = atomicAdd(&fcnt, 1);
        fslot[lp] = p; ftok[lp] = n0 + tid;
      }
    }
  }
  __syncthreads();

  // gather e[idx] (f32), write z_quant f32 (coalesced over hw), accumulate loss
  float lacc = 0.0f;
  {
    const int hw = tid & 63;
    const int sw = (hw & 7) ^ (hw >> 3);
    const float* erow = emb + (fidx[hw] << 8);
    #pragma unroll
    for (int it = 0; it < 8; it++) {
      const int dblk = (it << 2) + w;            // waves own disjoint dblk groups
      half8 zv = *(const half8*)(zt + (hw << 8) + ((dblk ^ sw) << 3));
      f32x4 e0 = *(const f32x4*)(erow + (dblk << 3));
      f32x4 e1 = *(const f32x4*)(erow + (dblk << 3) + 4);
      #pragma unroll
      for (int j = 0; j < 8; j++) {
        const int d = (dblk << 3) + j;
        const float ef = (j < 4) ? e0[j] : e1[j - 4];
        const float df = ef - (float)zv[j];
        lacc += df * df;
        out[(((b << 8) + d) << 10) + hw0 + hw] = ef;
      }
    }
  }
  #pragma unroll
  for (int m = 1; m < 64; m <<= 1) lacc += __shfl_xor(lacc, m);
  if (l == 0) lred[w] = lacc;
  __syncthreads();
  if (tid == 0) atomicAdd(&g_loss, lred[0] + lred[1] + lred[2] + lred[3]);

  // inline staging of this block's flagged tokens (~1.4 avg): exact f32 x
  // re-read -> coalesced g_zst row; A_n with the SAME f64 op order as pass 2.
  const int nf = fcnt;
  for (int f = 0; f < nf; f++) {
    const int s = fslot[f];
    const int n = ftok[f];
    const int bb = n >> 10, hw = n & 1023;
    const float zv = x[(((bb << 8) + tid) << 10) + hw];
    g_zst[(s << 8) + tid] = zv;
    ckl[tid] = zv;                               // ckl reused as zl (done with g_ck)
    __syncthreads();
    if (tid < 32) {
      double sa = 0.0;
      #pragma unroll
      for (int j = 0; j < 8; j++) { const double z = (double)ckl[(tid << 3) + j]; sa += z * z; }
      #pragma unroll
      for (int m = 1; m < 32; m <<= 1) sa += __shfl_xor(sa, m);
      if (tid == 0) g_aA[s] = (float)sa;
    }
    __syncthreads();
  }
}

// pass 2: job = (token-quad, r-quarter), njob ~ 732 over 768 blocks.
// __launch_bounds__(256,2) -> VGPR cap ~256: room for the hand-built 8-deep
// e-prefetch. z rows converted to f64 in LDS ONCE (cvt exact -> fma chain
// operands/order bit-identical to r4/r5). Per-lane d-ascending f64 chain,
// 4 chains ILP. Barrier-free shfl min-reduce + cross-wave merge. Last block
// finalizes (decode winners, rewrite changed z_quant rows, loss).
__global__ __launch_bounds__(256, 2) void vq_fix(const float* __restrict__ emb,
                                                 float* __restrict__ out) {
  __shared__ double zd0[256], zd1[256], zd2[256], zd3[256];  // 8 KB
  __shared__ float rv[4][4];
  __shared__ int   rk[4][4];
  __shared__ unsigned int chmask[FLAG_CAP / 32];   // 1 KB changed-token bitmap
  __shared__ int   lastflag;
  const int tid = threadIdx.x;
  int cnt = g_cnt; if (cnt > FLAG_CAP) cnt = FLAG_CAP;
  const int njob = ((cnt + 3) >> 2) << 2;
  for (int j = blockIdx.x; j < njob; j += gridDim.x) {
    const int grp = j >> 2, r = j & 3;
    const int s0 = grp << 2;
    const int s1 = (s0 + 1 < cnt) ? s0 + 1 : cnt - 1;
    const int s2 = (s0 + 2 < cnt) ? s0 + 2 : cnt - 1;
    const int s3 = (s0 + 3 < cnt) ? s0 + 3 : cnt - 1;
    zd0[tid] = (double)g_zst[(s0 << 8) + tid];
    zd1[tid] = (double)g_zst[(s1 << 8) + tid];
    zd2[tid] = (double)g_zst[(s2 << 8) + tid];
    zd3[tid] = (double)g_zst[(s3 << 8) + tid];
    __syncthreads();
    double c0 = 0.0, c1 = 0.0, c2 = 0.0, c3 = 0.0;
    const float* colbase = g_ebT + (r << 8) + tid;
    // 8-deep explicit prefetch pipeline over d-groups
    float ev0,ev1,ev2,ev3,ev4,ev5,ev6,ev7;
    ev0 = colbase[0 << 10]; ev1 = colbase[1 << 10];
    ev2 = colbase[2 << 10]; ev3 = colbase[3 << 10];
    ev4 = colbase[4 << 10]; ev5 = colbase[5 << 10];
    ev6 = colbase[6 << 10]; ev7 = colbase[7 << 10];
    #pragma unroll 1
    for (int dg = 0; dg < 32; dg++) {
      const int nb = ((dg < 31) ? (dg + 1) : 31) << 3;
      float nv0,nv1,nv2,nv3,nv4,nv5,nv6,nv7;
      nv0 = colbase[(nb + 0) << 10]; nv1 = colbase[(nb + 1) << 10];
      nv2 = colbase[(nb + 2) << 10]; nv3 = colbase[(nb + 3) << 10];
      nv4 = colbase[(nb + 4) << 10]; nv5 = colbase[(nb + 5) << 10];
      nv6 = colbase[(nb + 6) << 10]; nv7 = colbase[(nb + 7) << 10];
      const int d0 = dg << 3;
      #define FIX_STEP(EV, I) { const double e = (double)(EV); \
        c0 = fma(e, zd0[d0 + (I)], c0); c1 = fma(e, zd1[d0 + (I)], c1); \
        c2 = fma(e, zd2[d0 + (I)], c2); c3 = fma(e, zd3[d0 + (I)], c3); }
      FIX_STEP(ev0, 0) FIX_STEP(ev1, 1) FIX_STEP(ev2, 2) FIX_STEP(ev3, 3)
      FIX_STEP(ev4, 4) FIX_STEP(ev5, 5) FIX_STEP(ev6, 6) FIX_STEP(ev7, 7)
      #undef FIX_STEP
      ev0 = nv0; ev1 = nv1; ev2 = nv2; ev3 = nv3;
      ev4 = nv4; ev5 = nv5; ev6 = nv6; ev7 = nv7;
    }
    const int k = (r << 8) + tid;
    const float bkv = g_bk[k];
    float b0 = (g_aA[s0] + bkv) - 2.0f * (float)c0;
    float b1 = (g_aA[s1] + bkv) - 2.0f * (float)c1;
    float b2 = (g_aA[s2] + bkv) - 2.0f * (float)c2;
    float b3 = (g_aA[s3] + bkv) - 2.0f * (float)c3;
    int k0i = k, k1i = k, k2i = k, k3i = k;
    #pragma unroll
    for (int m = 1; m < 64; m <<= 1) {
      const float o0 = __shfl_xor(b0, m); const int x0 = __shfl_xor(k0i, m);
      const float o1 = __shfl_xor(b1, m); const int x1 = __shfl_xor(k1i, m);
      const float o2 = __shfl_xor(b2, m); const int x2 = __shfl_xor(k2i, m);
      const float o3 = __shfl_xor(b3, m); const int x3 = __shfl_xor(k3i, m);
      if (o0 < b0 || (o0 == b0 && x0 < k0i)) { b0 = o0; k0i = x0; }
      if (o1 < b1 || (o1 == b1 && x1 < k1i)) { b1 = o1; k1i = x1; }
      if (o2 < b2 || (o2 == b2 && x2 < k2i)) { b2 = o2; k2i = x2; }
      if (o3 < b3 || (o3 == b3 && x3 < k3i)) { b3 = o3; k3i = x3; }
    }
    const int wv = tid >> 6;
    if ((tid & 63) == 0) {
      rv[0][wv] = b0; rk[0][wv] = k0i; rv[1][wv] = b1; rk[1][wv] = k1i;
      rv[2][wv] = b2; rk[2][wv] = k2i; rv[3][wv] = b3; rk[3][wv] = k3i;
    }
    __syncthreads();
    if (tid == 0) {
      float fb[4]; int fk[4];
      #pragma unroll
      for (int g = 0; g < 4; g++) { fb[g] = rv[g][0]; fk[g] = rk[g][0]; }
      #pragma unroll
      for (int ww = 1; ww < 4; ww++)
        #pragma unroll
        for (int g = 0; g < 4; g++)
          if (rv[g][ww] < fb[g] || (rv[g][ww] == fb[g] && rk[g][ww] < fk[g])) {
            fb[g] = rv[g][ww]; fk[g] = rk[g][ww];
          }
      atomicMin(&g_best[s0], enc_dk(fb[0], fk[0]));
      atomicMin(&g_best[s1], enc_dk(fb[1], fk[1]));
      atomicMin(&g_best[s2], enc_dk(fb[2], fk[2]));
      atomicMin(&g_best[s3], enc_dk(fb[3], fk[3]));
    }
    __syncthreads();
  }

  // last-block finalize (device-scope atomics; g_best re-read atomically)
  __threadfence();
  if (tid == 0) lastflag = (atomicAdd(&g_fixdone, 1) == (int)gridDim.x - 1);
  __syncthreads();
  if (!lastflag) return;
  if (tid == 0) out[ZQ_ELEMS + N_TOK] = g_loss * (1.25f / 8388608.0f);
  for (int i = tid; i < FLAG_CAP / 32; i += 256) chmask[i] = 0u;
  __syncthreads();
  for (int s = tid; s < cnt; s += 256) {
    const int n = g_flags[s];
    const unsigned long long bv = atomicMin(&g_best[s], ~0ULL);  // coherent read
    const int kw = (int)(unsigned int)(bv & 0xFFFFFFFFu);
    const int kold = (int)out[ZQ_ELEMS + n];
    out[ZQ_ELEMS + n] = (float)kw;
    if (kw != kold) {
      g_flags[s] = (int)(((unsigned)n) | ((unsigned)kw << 15) | 0x80000000u);
      atomicOr(&chmask[s >> 5], 1u << (s & 31));
    }
  }
  __syncthreads();
  const int nw = (cnt + 31) >> 5;
  for (int wd = 0; wd < nw; wd++) {
    unsigned int m = chmask[wd];
    while (m) {
      const int bpos = __ffs(m) - 1;
      m &= m - 1;
      const int s = (wd << 5) + bpos;
      const unsigned pv = (unsigned)g_flags[s];    // written by this block, post-barrier
      const int n  = (int)(pv & 0x7FFFu);
      const int kw = (int)((pv >> 15) & 0x3FFu);
      const int bb = n >> 10, hw = n & 1023;
      out[(((bb << 8) + tid) << 10) + hw] = emb[(kw << 8) + tid];
    }
  }
}

extern "C" void kernel_launch(void* const* d_in, const int* in_sizes, int n_in,
                              void* d_out, int out_size, void* d_ws, size_t ws_size,
                              hipStream_t stream) {
  const float* x   = (const float*)d_in[0];
  const float* emb = (const float*)d_in[1];
  float* out = (float*)d_out;
  vq_prep<<<256, 256, 0, stream>>>(emb);
  vq_main<<<512, 256, 0, stream>>>(x, emb, out);
  vq_fix<<<FIX_GRID, 256, 0, stream>>>(emb, out);
}

// Round 7
// 204.409 us; speedup vs baseline: 1.6427x; 1.2761x over previous
//
#include <hip/hip_runtime.h>

typedef _Float16 half8 __attribute__((ext_vector_type(8)));
typedef _Float16 half4v __attribute__((ext_vector_type(4)));
typedef float f32x4 __attribute__((ext_vector_type(4)));

#define ZQ_ELEMS 8388608   // 32*256*32*32
#define N_TOK    32768
#define D_DIM    256
#define K_CB     1024

#define FLAG_CAP 8192      // observed cnt ~730 (deterministic input); 11x margin
#define ESCALE   1024.0f
#define TAU      0.15f     // flag margin (scaled units)
#define FIX_GRID 2048
#define OUT_GRID 512

__device__ __align__(16) _Float16 g_eh[K_CB * D_DIM];  // fp16(1024*e)
__device__ __align__(16) float g_ebT[D_DIM * K_CB];    // emb transposed [d][k], 1 MB
__device__ float g_ck[K_CB];                            // 512*||e_k||^2 (prefilter)
__device__ float g_bk[K_CB];                            // f32(sum e^2), np-style B_k
__device__ float g_loss;
__device__ int   g_cnt;
__device__ int   g_flags[FLAG_CAP];
__device__ float g_zst[FLAG_CAP * 256];                 // staged z rows (coalesced)
__device__ float g_aA[FLAG_CAP];                        // A_n per flagged token
__device__ unsigned long long g_best[FLAG_CAP];         // (orderedD<<32)|k, atomicMin

__device__ __forceinline__ unsigned long long enc_dk(float D, int k) {
  unsigned int b = __float_as_uint(D);
  unsigned int u = (b & 0x80000000u) ? ~b : (b | 0x80000000u);  // order-preserving
  return (((unsigned long long)u) << 32) | (unsigned int)k;
}

// prep: tables + zero accumulators + reset g_best + emb transpose
__global__ __launch_bounds__(256) void vq_prep(const float* __restrict__ emb) {
  __shared__ float tl[64][65];
  const int tid = threadIdx.x;
  const int w   = tid >> 6;
  const int l   = tid & 63;
  const int k   = (blockIdx.x << 2) + w;          // 256 blocks * 4 waves
  f32x4 v = *(const f32x4*)(emb + (k << 8) + (l << 2));
  double sd = (double)v[0]*v[0] + (double)v[1]*v[1] + (double)v[2]*v[2] + (double)v[3]*v[3];
  #pragma unroll
  for (int m = 1; m < 64; m <<= 1) sd += __shfl_xor(sd, m);
  if (l == 0) { g_bk[k] = (float)sd; g_ck[k] = 512.0f * (float)sd; }
  half4v h;
  h[0] = (_Float16)(v[0] * ESCALE); h[1] = (_Float16)(v[1] * ESCALE);
  h[2] = (_Float16)(v[2] * ESCALE); h[3] = (_Float16)(v[3] * ESCALE);
  *(half4v*)(g_eh + (k << 8) + (l << 2)) = h;
  const int gi = blockIdx.x * 256 + tid;
  if (gi < FLAG_CAP) g_best[gi] = ~0ULL;
  if (blockIdx.x == 0 && tid == 0) { g_loss = 0.0f; g_cnt = 0; }
  // transpose tile (blocks 0..63): emb [k][d] -> g_ebT [d][k]
  if (blockIdx.x < 64) {
    const int tx = tid & 63, ty = tid >> 6;
    const int k0 = (blockIdx.x & 15) << 6;
    const int d0 = (blockIdx.x >> 4) << 6;
    #pragma unroll
    for (int j = 0; j < 16; j++) {
      const int kk = (ty << 4) + j;
      tl[kk][tx] = emb[((k0 + kk) << 8) + d0 + tx];
    }
    __syncthreads();
    #pragma unroll
    for (int j = 0; j < 16; j++) {
      const int dd = (ty << 4) + j;
      g_ebT[((d0 + dd) << 10) + k0 + tx] = tl[tx][dd];
    }
  }
}

// main: r0-measured structure verbatim (512 blocks x 256 thr, 4 waves, 64
// tokens/block, 16 jj, VGPR 108, 63-65 us measured) + inline staging tail.
__global__ __launch_bounds__(256, 2) void vq_main(const float* __restrict__ x,
                                                  const float* __restrict__ emb,
                                                  float* __restrict__ out) {
  __shared__ __align__(16) _Float16 zt[64 * 256];   // 32 KB, XOR-swizzled
  __shared__ float ckl[K_CB];
  __shared__ float wv1[4][64], wv2[4][64];
  __shared__ int   wi1[4][64];
  __shared__ int   fidx[64];
  __shared__ float lred[4];
  __shared__ int   fcnt;
  __shared__ int   fslot[64], ftok[64];

  const int tid = threadIdx.x;
  const int n0  = blockIdx.x * 64;
  const int b   = blockIdx.x >> 4;
  const int hw0 = (blockIdx.x & 15) << 6;

  if (tid == 0) fcnt = 0;

  #pragma unroll
  for (int i = 0; i < 4; i++) ckl[tid + 256 * i] = g_ck[tid + 256 * i];

  // stage x tile -> fp16; (n,d) lives at n*256 + (((d>>3)^(n&7)^(n>>3))<<3) + (d&7)
  {
    const int hw8 = (tid & 7) << 3;
    const int dl  = tid >> 3;               // 0..31
    #pragma unroll
    for (int it = 0; it < 8; it++) {
      const int d = (it << 5) + dl;
      const float* src = x + (((b << 8) + d) << 10) + hw0 + hw8;
      f32x4 a0 = *(const f32x4*)src;
      f32x4 a1 = *(const f32x4*)(src + 4);
      _Float16 cv[8];
      cv[0]=(_Float16)a0[0]; cv[1]=(_Float16)a0[1]; cv[2]=(_Float16)a0[2]; cv[3]=(_Float16)a0[3];
      cv[4]=(_Float16)a1[0]; cv[5]=(_Float16)a1[1]; cv[6]=(_Float16)a1[2]; cv[7]=(_Float16)a1[3];
      const int blkx = d >> 3;
      #pragma unroll
      for (int i = 0; i < 8; i++) {
        const int n   = hw8 + i;
        const int blk = blkx ^ i ^ (tid & 7);
        zt[(n << 8) + (blk << 3) + (d & 7)] = cv[i];
      }
    }
  }
  __syncthreads();

  const int w = tid >> 6;
  const int l = tid & 63;
  const int c = l & 15;
  const int q = l >> 4;

  half8 af[4][8];
  #pragma unroll
  for (int t = 0; t < 4; t++) {
    const int n  = (t << 4) + c;
    const int sw = (n & 7) ^ (n >> 3);
    #pragma unroll
    for (int s = 0; s < 8; s++) {
      const int K = (s << 2) + q;
      af[t][s] = *(const half8*)(zt + (n << 8) + ((K ^ sw) << 3));
    }
  }

  float v1[4][4], v2[4][4]; int i1[4][4];
  #pragma unroll
  for (int t = 0; t < 4; t++)
    #pragma unroll
    for (int r = 0; r < 4; r++) { v1[t][r] = -3e38f; v2[t][r] = -3e38f; i1[t][r] = 0; }

  for (int jj = 0; jj < 16; jj++) {
    const int k0 = (w << 4) + (jj << 6);
    const float ckv = ckl[k0 + c];
    f32x4 acc[4];
    #pragma unroll
    for (int t = 0; t < 4; t++) acc[t] = f32x4{-ckv, -ckv, -ckv, -ckv};
    #pragma unroll
    for (int s = 0; s < 8; s++) {
      const half8 bf = *(const half8*)(g_eh + ((k0 + c) << 8) + (s << 5) + (q << 3));
      #pragma unroll
      for (int t = 0; t < 4; t++)
        acc[t] = __builtin_amdgcn_mfma_f32_16x16x32_f16(af[t][s], bf, acc[t], 0, 0, 0);
    }
    const int kk = k0 + c;
    #pragma unroll
    for (int t = 0; t < 4; t++)
      #pragma unroll
      for (int r = 0; r < 4; r++) {
        const float sv = acc[t][r];
        if (sv > v1[t][r]) { v2[t][r] = v1[t][r]; v1[t][r] = sv; i1[t][r] = kk; }
        else if (sv > v2[t][r]) v2[t][r] = sv;
      }
  }

  // top-2 merge across the 16 column lanes, then across waves
  #pragma unroll
  for (int t = 0; t < 4; t++)
    #pragma unroll
    for (int r = 0; r < 4; r++) {
      float a1v = v1[t][r], a2v = v2[t][r]; int ai = i1[t][r];
      #pragma unroll
      for (int m = 8; m >= 1; m >>= 1) {
        const float o1 = __shfl_xor(a1v, m);
        const int   oi = __shfl_xor(ai, m);
        const float o2 = __shfl_xor(a2v, m);
        if (o1 > a1v || (o1 == a1v && oi < ai)) { a2v = fmaxf(a1v, o2); a1v = o1; ai = oi; }
        else a2v = fmaxf(a2v, o1);
      }
      if (c == 0) {
        const int nl = (t << 4) + (q << 2) + r;
        wv1[w][nl] = a1v; wv2[w][nl] = a2v; wi1[w][nl] = ai;
      }
    }
  __syncthreads();

  if (tid < 64) {
    float a1v = wv1[0][tid], a2v = wv2[0][tid]; int ai = wi1[0][tid];
    #pragma unroll
    for (int ww = 1; ww < 4; ww++) {
      const float o1 = wv1[ww][tid]; const int oi = wi1[ww][tid]; const float o2 = wv2[ww][tid];
      if (o1 > a1v || (o1 == a1v && oi < ai)) { a2v = fmaxf(a1v, o2); a1v = o1; ai = oi; }
      else a2v = fmaxf(a2v, o1);
    }
    fidx[tid] = ai;
    out[ZQ_ELEMS + n0 + tid] = (float)ai;        // idx as f32
    if (a1v - a2v < TAU) {                       // ambiguous -> np-replicated pass 2
      int p = atomicAdd(&g_cnt, 1);
      if (p < FLAG_CAP) {
        g_flags[p] = n0 + tid;
        int lp = atomicAdd(&fcnt, 1);
        fslot[lp] = p; ftok[lp] = n0 + tid;
      }
    }
  }
  __syncthreads();

  // gather e[idx] (f32), write z_quant f32 (coalesced over hw), accumulate loss
  float lacc = 0.0f;
  {
    const int hw = tid & 63;
    const int sw = (hw & 7) ^ (hw >> 3);
    const float* erow = emb + (fidx[hw] << 8);
    #pragma unroll
    for (int it = 0; it < 8; it++) {
      const int dblk = (it << 2) + w;            // waves own disjoint dblk groups
      half8 zv = *(const half8*)(zt + (hw << 8) + ((dblk ^ sw) << 3));
      f32x4 e0 = *(const f32x4*)(erow + (dblk << 3));
      f32x4 e1 = *(const f32x4*)(erow + (dblk << 3) + 4);
      #pragma unroll
      for (int j = 0; j < 8; j++) {
        const int d = (dblk << 3) + j;
        const float ef = (j < 4) ? e0[j] : e1[j - 4];
        const float df = ef - (float)zv[j];
        lacc += df * df;
        out[(((b << 8) + d) << 10) + hw0 + hw] = ef;
      }
    }
  }
  #pragma unroll
  for (int m = 1; m < 64; m <<= 1) lacc += __shfl_xor(lacc, m);
  if (l == 0) lred[w] = lacc;
  __syncthreads();
  if (tid == 0) atomicAdd(&g_loss, lred[0] + lred[1] + lred[2] + lred[3]);

  // inline staging of this block's flagged tokens (~1.4 avg): exact f32 x
  // re-read -> coalesced g_zst row; A_n in f64 (32-lane tree).
  const int nf = fcnt;
  for (int f = 0; f < nf; f++) {
    const int s = fslot[f];
    const int n = ftok[f];
    const int bb = n >> 10, hw = n & 1023;
    const float zv = x[(((bb << 8) + tid) << 10) + hw];
    g_zst[(s << 8) + tid] = zv;
    ckl[tid] = zv;                               // ckl reused as zl (done with g_ck)
    __syncthreads();
    if (tid < 32) {
      double sa = 0.0;
      #pragma unroll
      for (int j = 0; j < 8; j++) { const double z = (double)ckl[(tid << 3) + j]; sa += z * z; }
      #pragma unroll
      for (int m = 1; m < 32; m <<= 1) sa += __shfl_xor(sa, m);
      if (tid == 0) g_aA[s] = (float)sa;
    }
    __syncthreads();
  }
}

// pass 2: job = (token-pair, r-quarter), njob = ceil(cnt/2)*4 ~ 1464 over 2048
// blocks (8/CU, all jobs in one round). Lane owns k = r*256 + tid. The dot is
// split into 4 INDEPENDENT d-quarter f64 chains per token (8 chains/thread):
// chain latency /4 and real load/fma overlap without relying on the register
// allocator's mood. Quarters summed in f64 (error ~1e-13 << 1e-4 gaps; final
// f32 combine formula and (v,k) tie-break unchanged). Shfl min-reduce + 4-way
// cross-wave merge -> one atomicMin per token. NO serial finalize here.
__global__ __launch_bounds__(256, 2) void vq_fix() {
  __shared__ float z0l[256], z1l[256];
  __shared__ float rv[2][4];
  __shared__ int   rk[2][4];
  const int tid = threadIdx.x;
  int cnt = g_cnt; if (cnt > FLAG_CAP) cnt = FLAG_CAP;
  const int njob = ((cnt + 1) >> 1) << 2;
  for (int j = blockIdx.x; j < njob; j += gridDim.x) {
    const int pr = j >> 2, r = j & 3;
    const int s0 = pr << 1;
    const int s1 = (s0 + 1 < cnt) ? s0 + 1 : cnt - 1;
    z0l[tid] = g_zst[(s0 << 8) + tid];
    z1l[tid] = g_zst[(s1 << 8) + tid];
    __syncthreads();
    double a0 = 0.0, a1 = 0.0, a2 = 0.0, a3 = 0.0;   // token0 d-quarter chains
    double b0 = 0.0, b1 = 0.0, b2 = 0.0, b3 = 0.0;   // token1 d-quarter chains
    const float* colbase = g_ebT + (r << 8) + tid;
    #pragma unroll 8
    for (int i = 0; i < 64; i++) {
      const double e0 = (double)colbase[(i      ) << 10];   // coalesced over tid
      const double e1 = (double)colbase[(i +  64) << 10];
      const double e2 = (double)colbase[(i + 128) << 10];
      const double e3 = (double)colbase[(i + 192) << 10];
      a0 = fma(e0, (double)z0l[i      ], a0);
      a1 = fma(e1, (double)z0l[i +  64], a1);
      a2 = fma(e2, (double)z0l[i + 128], a2);
      a3 = fma(e3, (double)z0l[i + 192], a3);
      b0 = fma(e0, (double)z1l[i      ], b0);
      b1 = fma(e1, (double)z1l[i +  64], b1);
      b2 = fma(e2, (double)z1l[i + 128], b2);
      b3 = fma(e3, (double)z1l[i + 192], b3);
    }
    const double c0 = (a0 + a1) + (a2 + a3);
    const double c1 = (b0 + b1) + (b2 + b3);
    const int k = (r << 8) + tid;
    const float bkv = g_bk[k];
    float v0 = (g_aA[s0] + bkv) - 2.0f * (float)c0;
    float v1 = (g_aA[s1] + bkv) - 2.0f * (float)c1;
    int k0i = k, k1i = k;
    #pragma unroll
    for (int m = 1; m < 64; m <<= 1) {
      const float o0 = __shfl_xor(v0, m); const int x0 = __shfl_xor(k0i, m);
      const float o1 = __shfl_xor(v1, m); const int x1 = __shfl_xor(k1i, m);
      if (o0 < v0 || (o0 == v0 && x0 < k0i)) { v0 = o0; k0i = x0; }
      if (o1 < v1 || (o1 == v1 && x1 < k1i)) { v1 = o1; k1i = x1; }
    }
    const int wv = tid >> 6;
    if ((tid & 63) == 0) { rv[0][wv] = v0; rk[0][wv] = k0i; rv[1][wv] = v1; rk[1][wv] = k1i; }
    __syncthreads();
    if (tid == 0) {
      float fb0 = rv[0][0]; int fk0 = rk[0][0];
      float fb1 = rv[1][0]; int fk1 = rk[1][0];
      #pragma unroll
      for (int ww = 1; ww < 4; ww++) {
        if (rv[0][ww] < fb0 || (rv[0][ww] == fb0 && rk[0][ww] < fk0)) { fb0 = rv[0][ww]; fk0 = rk[0][ww]; }
        if (rv[1][ww] < fb1 || (rv[1][ww] == fb1 && rk[1][ww] < fk1)) { fb1 = rv[1][ww]; fk1 = rk[1][ww]; }
      }
      atomicMin(&g_best[s0], enc_dk(fb0, fk0));
      atomicMin(&g_best[s1], enc_dk(fb1, fk1));
    }
    __syncthreads();
  }
}

// parallel finalize: decode winners, write idx, rewrite changed z_quant rows
// (the stride-4KB scatter is spread across 512 blocks, not one), write loss.
__global__ __launch_bounds__(256) void vq_out(const float* __restrict__ emb,
                                              float* __restrict__ out) {
  const int tid = threadIdx.x;
  if (blockIdx.x == 0 && tid == 0)
    out[ZQ_ELEMS + N_TOK] = g_loss * (1.25f / 8388608.0f);
  int cnt = g_cnt; if (cnt > FLAG_CAP) cnt = FLAG_CAP;
  for (int s = blockIdx.x; s < cnt; s += gridDim.x) {
    const int n = g_flags[s];
    const int kw = (int)(unsigned int)(g_best[s] & 0xFFFFFFFFu);
    const int kold = (int)out[ZQ_ELEMS + n];     // read by all threads first
    __syncthreads();                             // reads-before-overwrite
    if (tid == 0) out[ZQ_ELEMS + n] = (float)kw;
    if (kw != kold) {                            // stale e-row -> rewrite exactly
      const int bb = n >> 10, hw = n & 1023;
      out[(((bb << 8) + tid) << 10) + hw] = emb[(kw << 8) + tid];
    }
    __syncthreads();
  }
}

extern "C" void kernel_launch(void* const* d_in, const int* in_sizes, int n_in,
                              void* d_out, int out_size, void* d_ws, size_t ws_size,
                              hipStream_t stream) {
  const float* x   = (const float*)d_in[0];
  const float* emb = (const float*)d_in[1];
  float* out = (float*)d_out;
  vq_prep<<<256, 256, 0, stream>>>(emb);
  vq_main<<<512, 256, 0, stream>>>(x, emb, out);
  vq_fix<<<FIX_GRID, 256, 0, stream>>>();
  vq_out<<<OUT_GRID, 256, 0, stream>>>(emb, out);
}